// Round 17
// baseline (602.654 us; speedup 1.0000x reference)
//
#include <hip/hip_runtime.h>
#include <hip/hip_cooperative_groups.h>
#include <hip/hip_bf16.h>

namespace cg = cooperative_groups;

#define N_NODES 16384
#define N_EDGES 524288
#define ZROW N_NODES       // sentinel row: xt[ZROW][*] == 0, deg[ZROW] == 0
#define ROWCAP 96          // Poisson(32) tail @96 ~ 1e-18/row; write guarded
#define NBLK 1024          // coop grid: 4 blocks/CU

// ---- workspace layout (bytes) ----
#define ROWCNT_OFF 0u                        // int[16384]   } contiguous,
#define DEG_OFF    65536u                    // int[16385]   } zeroed together
#define XT_OFF     131200u                   // bf16[(N+1)*64], 128B-aligned
#define COLIDX_OFF (XT_OFF + 2097280u)       // ushort[16384*96] = 3 MiB

// ============ cooperative fused kernel (phases = proven k1..k4) ============
__global__ __launch_bounds__(256, 4) void gcn_fused(
    const float* __restrict__ x, const int* __restrict__ ei,
    const float* __restrict__ theta,
    int* __restrict__ rowcnt, int* __restrict__ deg,
    __hip_bfloat16* __restrict__ xt, unsigned short* __restrict__ colidx,
    float* __restrict__ out)
{
    cg::grid_group grid = cg::this_grid();
    const int tid  = threadIdx.x;
    const int gtid = blockIdx.x * 256 + tid;
    const int nthr = NBLK * 256;             // 262144
    const int lane = tid & 63;
    const int wid  = gtid >> 6;              // 4096 global waves
    const int nw   = nthr >> 6;

    __shared__ float th[64 * 64];

    // ---- P0: zero rowcnt+deg (contiguous 32769 ints), sentinel row, GEMM
    for (int i = gtid; i < 2 * N_NODES + 1; i += nthr) rowcnt[i] = 0;
    if (gtid < 64) xt[ZROW * 64 + gtid] = __float2bfloat16(0.f);
    for (int i = tid; i < 64 * 64; i += 256) th[i] = theta[i];
    __syncthreads();
    for (int rb = blockIdx.x * 4; rb < N_NODES; rb += NBLK * 4) {
        int row = rb + (tid >> 6);
        const float* xr = x + row * 64;
        float acc = 0.f;
#pragma unroll
        for (int k = 0; k < 64; ++k) acc += xr[k] * th[k * 64 + lane];
        xt[row * 64 + lane] = __float2bfloat16(acc);
    }
    grid.sync();

    // ---- P1: bin edges
    for (int e = gtid; e < N_EDGES; e += nthr) {
        int r = ei[e];
        int c = ei[N_EDGES + e];
        int cnt = atomicAdd(&rowcnt[r], 1);
        if (cnt < ROWCAP) colidx[r * ROWCAP + cnt] = (unsigned short)c;
    }
    grid.sync();

    // ---- P2: per-row dedupe + column degree (race-safe: first occurrence
    // never overwritten; stale pre-ZROW read is the original value)
    for (int r = wid; r < N_NODES; r += nw) {
        int cnt = rowcnt[r]; if (cnt > ROWCAP) cnt = ROWCAP;
        int base = r * ROWCAP;
        for (int p = lane; p < cnt; p += 64) {
            int val = colidx[base + p];
            bool dup = (val == r);
            for (int j = 0; j < p; ++j) dup |= ((int)colidx[base + j] == val);
            if (dup) colidx[base + p] = (unsigned short)ZROW;
            else atomicAdd(&deg[val], 1);
        }
    }
    grid.sync();

    // ---- P3: gather with on-the-fly D^{-1/2}
    for (int r = wid; r < N_NODES; r += nw) {
        int cnt = rowcnt[r]; if (cnt > ROWCAP) cnt = ROWCAP;
        int base = r * ROWCAP;
        float dr = rsqrtf((float)(deg[r] + 1));
        float acc0 = dr * __bfloat162float(xt[r * 64 + lane]);
        float acc1 = 0.f, acc2 = 0.f, acc3 = 0.f;
        int p = 0;
        for (; p + 3 < cnt; p += 4) {
            int c0 = colidx[base + p];
            int c1 = colidx[base + p + 1];
            int c2 = colidx[base + p + 2];
            int c3 = colidx[base + p + 3];
            float d0 = rsqrtf((float)(deg[c0] + 1));
            float d1 = rsqrtf((float)(deg[c1] + 1));
            float d2 = rsqrtf((float)(deg[c2] + 1));
            float d3 = rsqrtf((float)(deg[c3] + 1));
            acc0 += d0 * __bfloat162float(xt[c0 * 64 + lane]);
            acc1 += d1 * __bfloat162float(xt[c1 * 64 + lane]);
            acc2 += d2 * __bfloat162float(xt[c2 * 64 + lane]);
            acc3 += d3 * __bfloat162float(xt[c3 * 64 + lane]);
        }
        for (; p < cnt; ++p) {
            int c = colidx[base + p];
            acc0 += rsqrtf((float)(deg[c] + 1)) * __bfloat162float(xt[c * 64 + lane]);
        }
        out[r * 64 + lane] = dr * ((acc0 + acc1) + (acc2 + acc3));
    }
}

// ============ fallback: proven 4-kernel pipeline (round 15) ============
__global__ __launch_bounds__(256) void k1_zero_gemm(
    const float* __restrict__ x, const float* __restrict__ theta,
    int* __restrict__ rowcnt, int* __restrict__ deg,
    __hip_bfloat16* __restrict__ xt) {
    int tid = threadIdx.x;
    int gtid = blockIdx.x * 256 + tid;
    if (gtid < N_NODES) rowcnt[gtid] = 0;
    else if (gtid < 2 * N_NODES + 1) deg[gtid - N_NODES] = 0;
    if (gtid < 64) xt[ZROW * 64 + gtid] = __float2bfloat16(0.f);

    __shared__ float th[64 * 64];
    for (int i = tid; i < 64 * 64; i += 256) th[i] = theta[i];
    __syncthreads();
    int row = blockIdx.x * 4 + (tid >> 6);
    int col = tid & 63;
    const float* xr = x + row * 64;
    float acc = 0.f;
#pragma unroll
    for (int k = 0; k < 64; ++k) acc += xr[k] * th[k * 64 + col];
    xt[row * 64 + col] = __float2bfloat16(acc);
}

__global__ void k2_bin(const int* __restrict__ ei,
                       int* __restrict__ rowcnt,
                       unsigned short* __restrict__ colidx) {
    int e = blockIdx.x * 256 + threadIdx.x;
    int r = ei[e];
    int c = ei[N_EDGES + e];
    int cnt = atomicAdd(&rowcnt[r], 1);
    if (cnt < ROWCAP) colidx[r * ROWCAP + cnt] = (unsigned short)c;
}

__global__ void k3_dedupe(const int* __restrict__ rowcnt,
                          unsigned short* __restrict__ colidx,
                          int* __restrict__ deg) {
    int lane = threadIdx.x & 63;
    int r = blockIdx.x * 4 + (threadIdx.x >> 6);
    int cnt = rowcnt[r]; if (cnt > ROWCAP) cnt = ROWCAP;
    int base = r * ROWCAP;
    for (int p = lane; p < cnt; p += 64) {
        int val = colidx[base + p];
        bool dup = (val == r);
        for (int j = 0; j < p; ++j) dup |= ((int)colidx[base + j] == val);
        if (dup) colidx[base + p] = (unsigned short)ZROW;
        else atomicAdd(&deg[val], 1);
    }
}

__global__ void k4_gather(const int* __restrict__ rowcnt,
                          const unsigned short* __restrict__ colidx,
                          const int* __restrict__ deg,
                          const __hip_bfloat16* __restrict__ xt,
                          float* __restrict__ out) {
    int lane = threadIdx.x & 63;
    int r = blockIdx.x * 4 + (threadIdx.x >> 6);
    int cnt = rowcnt[r]; if (cnt > ROWCAP) cnt = ROWCAP;
    int base = r * ROWCAP;
    float dr = rsqrtf((float)(deg[r] + 1));
    float acc0 = dr * __bfloat162float(xt[r * 64 + lane]);
    float acc1 = 0.f, acc2 = 0.f, acc3 = 0.f;
    int p = 0;
    for (; p + 3 < cnt; p += 4) {
        int c0 = colidx[base + p];
        int c1 = colidx[base + p + 1];
        int c2 = colidx[base + p + 2];
        int c3 = colidx[base + p + 3];
        float d0 = rsqrtf((float)(deg[c0] + 1));
        float d1 = rsqrtf((float)(deg[c1] + 1));
        float d2 = rsqrtf((float)(deg[c2] + 1));
        float d3 = rsqrtf((float)(deg[c3] + 1));
        acc0 += d0 * __bfloat162float(xt[c0 * 64 + lane]);
        acc1 += d1 * __bfloat162float(xt[c1 * 64 + lane]);
        acc2 += d2 * __bfloat162float(xt[c2 * 64 + lane]);
        acc3 += d3 * __bfloat162float(xt[c3 * 64 + lane]);
    }
    for (; p < cnt; ++p) {
        int c = colidx[base + p];
        acc0 += rsqrtf((float)(deg[c] + 1)) * __bfloat162float(xt[c * 64 + lane]);
    }
    out[r * 64 + lane] = dr * ((acc0 + acc1) + (acc2 + acc3));
}

extern "C" void kernel_launch(void* const* d_in, const int* in_sizes, int n_in,
                              void* d_out, int out_size, void* d_ws, size_t ws_size,
                              hipStream_t stream) {
    const float* x     = (const float*)d_in[0];
    const int*   ei    = (const int*)d_in[1];
    const float* theta = (const float*)d_in[2];
    float* out = (float*)d_out;

    char* ws = (char*)d_ws;
    int*            rowcnt = (int*)(ws + ROWCNT_OFF);
    int*            deg    = (int*)(ws + DEG_OFF);
    __hip_bfloat16* xt     = (__hip_bfloat16*)(ws + XT_OFF);
    unsigned short* colidx = (unsigned short*)(ws + COLIDX_OFF);

    void* args[] = { (void*)&x, (void*)&ei, (void*)&theta, (void*)&rowcnt,
                     (void*)&deg, (void*)&xt, (void*)&colidx, (void*)&out };
    hipError_t err = hipLaunchCooperativeKernel((const void*)gcn_fused,
                                                dim3(NBLK), dim3(256),
                                                args, 0, stream);
    if (err != hipSuccess) {
        // deterministic fallback: proven 4-kernel pipeline
        k1_zero_gemm<<<N_NODES / 4, 256, 0, stream>>>(x, theta, rowcnt, deg, xt);
        k2_bin      <<<N_EDGES / 256, 256, 0, stream>>>(ei, rowcnt, colidx);
        k3_dedupe   <<<N_NODES / 4, 256, 0, stream>>>(rowcnt, colidx, deg);
        k4_gather   <<<N_NODES / 4, 256, 0, stream>>>(rowcnt, colidx, deg, xt, out);
    }
}